// Round 1
// baseline (176.386 us; speedup 1.0000x reference)
//
#include <hip/hip_runtime.h>
#include <math.h>

// Problem constants (from reference setup_inputs)
#define CDIM 5
constexpr int B_ = 16;
constexpr int C_ = 256;
constexpr int HW_ = 128 * 128;     // 16384 elements per (b,c) plane
constexpr float MOM = 0.1f;

// ---------------------------------------------------------------------------
// Kernel 1: per-plane mean / std.  One block per (b,c) plane.
// 256 threads x 16 float4 loads = 16384 floats.
// ---------------------------------------------------------------------------
__global__ __launch_bounds__(256) void cin_stats(const float* __restrict__ im,
                                                 float* __restrict__ ws_mean,
                                                 float* __restrict__ ws_std) {
    const int plane = blockIdx.x;                // b*C + c
    const float4* p4 = (const float4*)(im + (size_t)plane * HW_);
    const int t = threadIdx.x;

    float sum = 0.f, sumsq = 0.f;
    #pragma unroll
    for (int it = 0; it < 16; ++it) {
        float4 v = p4[it * 256 + t];
        sum   += v.x + v.y + v.z + v.w;
        sumsq += v.x * v.x + v.y * v.y + v.z * v.z + v.w * v.w;
    }

    // wave64 butterfly reduce
    #pragma unroll
    for (int off = 32; off > 0; off >>= 1) {
        sum   += __shfl_down(sum, off, 64);
        sumsq += __shfl_down(sumsq, off, 64);
    }

    __shared__ float s_sum[4], s_sq[4];
    const int wave = t >> 6;
    if ((t & 63) == 0) { s_sum[wave] = sum; s_sq[wave] = sumsq; }
    __syncthreads();

    if (t == 0) {
        float s = s_sum[0] + s_sum[1] + s_sum[2] + s_sum[3];
        float q = s_sq[0] + s_sq[1] + s_sq[2] + s_sq[3];
        float mean = s / (float)HW_;
        // var = (sumsq - N*mean^2) / (N-1) = (q - s*mean) / (N-1)
        float var = fmaxf(q - s * mean, 0.f) / (float)(HW_ - 1);
        ws_mean[plane] = mean;
        ws_std[plane]  = sqrtf(var);
    }
}

// ---------------------------------------------------------------------------
// Kernel 2: sequential scan over batches updating running stats, then
// per-(b,c) target stats -> scale/shift.  Single block, 256 threads
// (thread t owns channel t; its 10 concat-rows live in registers).
// ---------------------------------------------------------------------------
__global__ __launch_bounds__(256) void cin_scan(const float* __restrict__ running_mean,
                                                const float* __restrict__ running_std,
                                                const int* __restrict__ c_trg,
                                                const int* __restrict__ c_org,
                                                const float* __restrict__ ws_mean,
                                                const float* __restrict__ ws_std,
                                                float* __restrict__ ws_scale,
                                                float* __restrict__ ws_shift) {
    const int t = threadIdx.x;   // channel index, 0..255

    float rm[2 * CDIM], rs[2 * CDIM];
    #pragma unroll
    for (int r = 0; r < 2 * CDIM; ++r) {
        rm[r] = running_mean[r * C_ + t];
        rs[r] = running_std [r * C_ + t];
    }

    // Sequential scan over the batch dimension
    for (int n = 0; n < B_; ++n) {
        const float mn = ws_mean[n * C_ + t];
        const float sd = ws_std [n * C_ + t];
        #pragma unroll
        for (int r = 0; r < 2 * CDIM; ++r) {
            const int k = (r < CDIM) ? r : r - CDIM;
            const int bit = c_org[n * CDIM + k];
            const bool msk = (r < CDIM) ? (bit != 0) : (bit == 0);
            if (msk) {
                rs[r] = rs[r] * (1.f - MOM) + sd * MOM;
                rm[r] = rm[r] * (1.f - MOM) + mn * MOM;
            }
        }
    }

    __shared__ float s_rm[2 * CDIM * C_], s_rs[2 * CDIM * C_];
    #pragma unroll
    for (int r = 0; r < 2 * CDIM; ++r) {
        s_rm[r * C_ + t] = rm[r];
        s_rs[r * C_ + t] = rs[r];
    }
    __syncthreads();

    // Per-(b, c): trg stats -> scale/shift
    for (int b = 0; b < B_; ++b) {
        float cnt = 0.f, tm = 0.f, ts = 0.f;
        #pragma unroll
        for (int r = 0; r < 2 * CDIM; ++r) {
            const int k = (r < CDIM) ? r : r - CDIM;
            const int bit = c_trg[b * CDIM + k];
            const bool sel = (r < CDIM) ? (bit != 0) : (bit == 0);
            if (sel) {
                cnt += 1.f;
                tm  += s_rm[r * C_ + t];
                ts  += s_rs[r * C_ + t];
            }
        }
        tm /= cnt;
        ts /= cnt;
        const int plane = b * C_ + t;
        const float mean = ws_mean[plane];
        const float std  = ws_std [plane];
        const float scale = ts / std;
        ws_scale[plane] = scale;
        ws_shift[plane] = tm - mean * scale;
    }
}

// ---------------------------------------------------------------------------
// Kernel 3: out = im * scale[plane] + shift[plane].  One block per plane.
// ---------------------------------------------------------------------------
__global__ __launch_bounds__(256) void cin_norm(const float* __restrict__ im,
                                                const float* __restrict__ ws_scale,
                                                const float* __restrict__ ws_shift,
                                                float* __restrict__ out) {
    const int plane = blockIdx.x;
    const float scale = ws_scale[plane];
    const float shift = ws_shift[plane];
    const float4* p4 = (const float4*)(im + (size_t)plane * HW_);
    float4*       o4 = (float4*)(out + (size_t)plane * HW_);
    const int t = threadIdx.x;

    #pragma unroll
    for (int it = 0; it < 16; ++it) {
        float4 v = p4[it * 256 + t];
        float4 r;
        r.x = fmaf(v.x, scale, shift);
        r.y = fmaf(v.y, scale, shift);
        r.z = fmaf(v.z, scale, shift);
        r.w = fmaf(v.w, scale, shift);
        o4[it * 256 + t] = r;
    }
}

// ---------------------------------------------------------------------------
extern "C" void kernel_launch(void* const* d_in, const int* in_sizes, int n_in,
                              void* d_out, int out_size, void* d_ws, size_t ws_size,
                              hipStream_t stream) {
    const float* im           = (const float*)d_in[0];
    const float* running_mean = (const float*)d_in[1];
    const float* running_std  = (const float*)d_in[2];
    const int*   c_trg        = (const int*)d_in[3];
    const int*   c_org        = (const int*)d_in[4];
    float* out = (float*)d_out;

    // Workspace layout (floats): mean[4096] | std[4096] | scale[4096] | shift[4096]
    float* ws       = (float*)d_ws;
    float* ws_mean  = ws;
    float* ws_std   = ws + B_ * C_;
    float* ws_scale = ws + 2 * B_ * C_;
    float* ws_shift = ws + 3 * B_ * C_;

    const int planes = B_ * C_;   // 4096

    cin_stats<<<planes, 256, 0, stream>>>(im, ws_mean, ws_std);
    cin_scan<<<1, 256, 0, stream>>>(running_mean, running_std, c_trg, c_org,
                                    ws_mean, ws_std, ws_scale, ws_shift);
    cin_norm<<<planes, 256, 0, stream>>>(im, ws_scale, ws_shift, out);
}

// Round 2
// 135.371 us; speedup vs baseline: 1.3030x; 1.3030x over previous
//
#include <hip/hip_runtime.h>
#include <math.h>

// Problem constants (from reference setup_inputs)
#define CDIM 5
constexpr int B_ = 16;
constexpr int C_ = 256;
constexpr int HW_ = 128 * 128;     // 16384 elements per (b,c) plane
constexpr float MOM = 0.1f;

using f32x4 = __attribute__((ext_vector_type(4))) float;

// ---------------------------------------------------------------------------
// Kernel 1: per-plane mean / std.  One block per (b,c) plane.
// 256 threads x 16 float4 loads = 16384 floats.  Normal (caching) loads so
// im becomes L3-resident (im is exactly 256 MiB == Infinity Cache size).
// ---------------------------------------------------------------------------
__global__ __launch_bounds__(256) void cin_stats(const float* __restrict__ im,
                                                 float* __restrict__ ws_mean,
                                                 float* __restrict__ ws_std) {
    const int plane = blockIdx.x;                // b*C + c
    const f32x4* p4 = (const f32x4*)(im + (size_t)plane * HW_);
    const int t = threadIdx.x;

    float sum = 0.f, sumsq = 0.f;
    #pragma unroll
    for (int it = 0; it < 16; ++it) {
        f32x4 v = p4[it * 256 + t];
        sum   += v.x + v.y + v.z + v.w;
        sumsq += v.x * v.x + v.y * v.y + v.z * v.z + v.w * v.w;
    }

    // wave64 butterfly reduce
    #pragma unroll
    for (int off = 32; off > 0; off >>= 1) {
        sum   += __shfl_down(sum, off, 64);
        sumsq += __shfl_down(sumsq, off, 64);
    }

    __shared__ float s_sum[4], s_sq[4];
    const int wave = t >> 6;
    if ((t & 63) == 0) { s_sum[wave] = sum; s_sq[wave] = sumsq; }
    __syncthreads();

    if (t == 0) {
        float s = s_sum[0] + s_sum[1] + s_sum[2] + s_sum[3];
        float q = s_sq[0] + s_sq[1] + s_sq[2] + s_sq[3];
        float mean = s / (float)HW_;
        // var = (sumsq - N*mean^2) / (N-1) = (q - s*mean) / (N-1)
        float var = fmaxf(q - s * mean, 0.f) / (float)(HW_ - 1);
        ws_mean[plane] = mean;
        ws_std[plane]  = sqrtf(var);
    }
}

// ---------------------------------------------------------------------------
// Kernel 2: sequential scan over batches updating running stats, then
// per-(b,c) target stats -> scale/shift.  Single block, 256 threads
// (thread t owns channel t; its 10 concat-rows live in registers).
// ---------------------------------------------------------------------------
__global__ __launch_bounds__(256) void cin_scan(const float* __restrict__ running_mean,
                                                const float* __restrict__ running_std,
                                                const int* __restrict__ c_trg,
                                                const int* __restrict__ c_org,
                                                const float* __restrict__ ws_mean,
                                                const float* __restrict__ ws_std,
                                                float* __restrict__ ws_scale,
                                                float* __restrict__ ws_shift) {
    const int t = threadIdx.x;   // channel index, 0..255

    float rm[2 * CDIM], rs[2 * CDIM];
    #pragma unroll
    for (int r = 0; r < 2 * CDIM; ++r) {
        rm[r] = running_mean[r * C_ + t];
        rs[r] = running_std [r * C_ + t];
    }

    // Sequential scan over the batch dimension
    for (int n = 0; n < B_; ++n) {
        const float mn = ws_mean[n * C_ + t];
        const float sd = ws_std [n * C_ + t];
        #pragma unroll
        for (int r = 0; r < 2 * CDIM; ++r) {
            const int k = (r < CDIM) ? r : r - CDIM;
            const int bit = c_org[n * CDIM + k];
            const bool msk = (r < CDIM) ? (bit != 0) : (bit == 0);
            if (msk) {
                rs[r] = rs[r] * (1.f - MOM) + sd * MOM;
                rm[r] = rm[r] * (1.f - MOM) + mn * MOM;
            }
        }
    }

    __shared__ float s_rm[2 * CDIM * C_], s_rs[2 * CDIM * C_];
    #pragma unroll
    for (int r = 0; r < 2 * CDIM; ++r) {
        s_rm[r * C_ + t] = rm[r];
        s_rs[r * C_ + t] = rs[r];
    }
    __syncthreads();

    // Per-(b, c): trg stats -> scale/shift
    for (int b = 0; b < B_; ++b) {
        float cnt = 0.f, tm = 0.f, ts = 0.f;
        #pragma unroll
        for (int r = 0; r < 2 * CDIM; ++r) {
            const int k = (r < CDIM) ? r : r - CDIM;
            const int bit = c_trg[b * CDIM + k];
            const bool sel = (r < CDIM) ? (bit != 0) : (bit == 0);
            if (sel) {
                cnt += 1.f;
                tm  += s_rm[r * C_ + t];
                ts  += s_rs[r * C_ + t];
            }
        }
        tm /= cnt;
        ts /= cnt;
        const int plane = b * C_ + t;
        const float mean = ws_mean[plane];
        const float std  = ws_std [plane];
        const float scale = ts / std;
        ws_scale[plane] = scale;
        ws_shift[plane] = tm - mean * scale;
    }
}

// ---------------------------------------------------------------------------
// Kernel 3: out = im * scale[plane] + shift[plane].  One block per plane.
// Loads of im are normal (hit L3, keep it resident); stores of out are
// NONTEMPORAL so the 256 MiB out stream does not evict im from L3.
// ---------------------------------------------------------------------------
__global__ __launch_bounds__(256) void cin_norm(const float* __restrict__ im,
                                                const float* __restrict__ ws_scale,
                                                const float* __restrict__ ws_shift,
                                                float* __restrict__ out) {
    const int plane = blockIdx.x;
    const float scale = ws_scale[plane];
    const float shift = ws_shift[plane];
    const f32x4* p4 = (const f32x4*)(im + (size_t)plane * HW_);
    f32x4*       o4 = (f32x4*)(out + (size_t)plane * HW_);
    const int t = threadIdx.x;

    #pragma unroll
    for (int it = 0; it < 16; ++it) {
        f32x4 v = p4[it * 256 + t];
        f32x4 r;
        r.x = fmaf(v.x, scale, shift);
        r.y = fmaf(v.y, scale, shift);
        r.z = fmaf(v.z, scale, shift);
        r.w = fmaf(v.w, scale, shift);
        __builtin_nontemporal_store(r, &o4[it * 256 + t]);
    }
}

// ---------------------------------------------------------------------------
extern "C" void kernel_launch(void* const* d_in, const int* in_sizes, int n_in,
                              void* d_out, int out_size, void* d_ws, size_t ws_size,
                              hipStream_t stream) {
    const float* im           = (const float*)d_in[0];
    const float* running_mean = (const float*)d_in[1];
    const float* running_std  = (const float*)d_in[2];
    const int*   c_trg        = (const int*)d_in[3];
    const int*   c_org        = (const int*)d_in[4];
    float* out = (float*)d_out;

    // Workspace layout (floats): mean[4096] | std[4096] | scale[4096] | shift[4096]
    float* ws       = (float*)d_ws;
    float* ws_mean  = ws;
    float* ws_std   = ws + B_ * C_;
    float* ws_scale = ws + 2 * B_ * C_;
    float* ws_shift = ws + 3 * B_ * C_;

    const int planes = B_ * C_;   // 4096

    cin_stats<<<planes, 256, 0, stream>>>(im, ws_mean, ws_std);
    cin_scan<<<1, 256, 0, stream>>>(running_mean, running_std, c_trg, c_org,
                                    ws_mean, ws_std, ws_scale, ws_shift);
    cin_norm<<<planes, 256, 0, stream>>>(im, ws_scale, ws_shift, out);
}

// Round 3
// 128.284 us; speedup vs baseline: 1.3750x; 1.0552x over previous
//
#include <hip/hip_runtime.h>
#include <math.h>

// Problem constants (from reference setup_inputs)
#define CDIM 5
constexpr int B_ = 16;
constexpr int C_ = 256;
constexpr int HW_ = 128 * 128;     // 16384 elements per (b,c) plane
constexpr float MOM = 0.1f;

using f32x4 = __attribute__((ext_vector_type(4))) float;

// ---------------------------------------------------------------------------
// Kernel 1: per-plane mean / std.  One block per (b,c) plane.
// 256 threads x 16 float4 loads = 16384 floats.  Normal (caching) loads so
// im becomes L3-resident (im is exactly 256 MiB == Infinity Cache size).
// ---------------------------------------------------------------------------
__global__ __launch_bounds__(256) void cin_stats(const float* __restrict__ im,
                                                 float* __restrict__ ws_mean,
                                                 float* __restrict__ ws_std) {
    const int plane = blockIdx.x;                // b*C + c
    const f32x4* p4 = (const f32x4*)(im + (size_t)plane * HW_);
    const int t = threadIdx.x;

    float sum = 0.f, sumsq = 0.f;
    #pragma unroll
    for (int it = 0; it < 16; ++it) {
        f32x4 v = p4[it * 256 + t];
        sum   += v.x + v.y + v.z + v.w;
        sumsq += v.x * v.x + v.y * v.y + v.z * v.z + v.w * v.w;
    }

    // wave64 butterfly reduce
    #pragma unroll
    for (int off = 32; off > 0; off >>= 1) {
        sum   += __shfl_down(sum, off, 64);
        sumsq += __shfl_down(sumsq, off, 64);
    }

    __shared__ float s_sum[4], s_sq[4];
    const int wave = t >> 6;
    if ((t & 63) == 0) { s_sum[wave] = sum; s_sq[wave] = sumsq; }
    __syncthreads();

    if (t == 0) {
        float s = s_sum[0] + s_sum[1] + s_sum[2] + s_sum[3];
        float q = s_sq[0] + s_sq[1] + s_sq[2] + s_sq[3];
        float mean = s / (float)HW_;
        // var = (sumsq - N*mean^2) / (N-1) = (q - s*mean) / (N-1)
        float var = fmaxf(q - s * mean, 0.f) / (float)(HW_ - 1);
        ws_mean[plane] = mean;
        ws_std[plane]  = sqrtf(var);
    }
}

// ---------------------------------------------------------------------------
// Kernel 2: batch-scan of running stats.  2560 independent chains (r, c);
// 10 blocks x 256 threads, one chain per thread.  The per-batch mask is
// block-uniform (depends only on r = blockIdx), so no divergence.
// ---------------------------------------------------------------------------
__global__ __launch_bounds__(256) void cin_scan(const float* __restrict__ running_mean,
                                                const float* __restrict__ running_std,
                                                const int* __restrict__ c_org,
                                                const float* __restrict__ ws_mean,
                                                const float* __restrict__ ws_std,
                                                float* __restrict__ ws_rm,
                                                float* __restrict__ ws_rs) {
    const int r = blockIdx.x;    // 0..9 concat-row
    const int c = threadIdx.x;   // 0..255 channel

    float rm = running_mean[r * C_ + c];
    float rs = running_std [r * C_ + c];
    const int k = (r < CDIM) ? r : r - CDIM;

    for (int n = 0; n < B_; ++n) {
        const int bit = c_org[n * CDIM + k];
        const bool msk = (r < CDIM) ? (bit != 0) : (bit == 0);
        if (msk) {
            rs = rs * (1.f - MOM) + ws_std [n * C_ + c] * MOM;
            rm = rm * (1.f - MOM) + ws_mean[n * C_ + c] * MOM;
        }
    }
    ws_rm[r * C_ + c] = rm;
    ws_rs[r * C_ + c] = rs;
}

// ---------------------------------------------------------------------------
// Kernel 3: out = im * scale + shift.  One block per plane, REVERSE order:
// block 0 handles plane 4095 (the most recently L3-cached by cin_stats), so
// reads hit Infinity Cache before LRU eviction reaches them.  Each block
// computes its own scale/shift from block-uniform scalar loads (~22 loads,
// L2-hot).  Stores are NONTEMPORAL so the out stream doesn't evict im.
// ---------------------------------------------------------------------------
__global__ __launch_bounds__(256) void cin_norm(const float* __restrict__ im,
                                                const float* __restrict__ ws_mean,
                                                const float* __restrict__ ws_std,
                                                const float* __restrict__ ws_rm,
                                                const float* __restrict__ ws_rs,
                                                const int* __restrict__ c_trg,
                                                float* __restrict__ out) {
    const int plane = (B_ * C_ - 1) - blockIdx.x;   // reverse order
    const int b = plane >> 8;           // plane / C_
    const int c = plane & (C_ - 1);     // plane % C_

    // Per-plane target stats (uniform across the block -> scalarized)
    float tm = 0.f, ts = 0.f, cnt = 0.f;
    #pragma unroll
    for (int r = 0; r < 2 * CDIM; ++r) {
        const int k = (r < CDIM) ? r : r - CDIM;
        const int bit = c_trg[b * CDIM + k];
        const bool sel = (r < CDIM) ? (bit != 0) : (bit == 0);
        if (sel) {
            cnt += 1.f;
            tm  += ws_rm[r * C_ + c];
            ts  += ws_rs[r * C_ + c];
        }
    }
    tm /= cnt;
    ts /= cnt;
    const float mean  = ws_mean[plane];
    const float std   = ws_std [plane];
    const float scale = ts / std;
    const float shift = tm - mean * scale;

    const f32x4* p4 = (const f32x4*)(im + (size_t)plane * HW_);
    f32x4*       o4 = (f32x4*)(out + (size_t)plane * HW_);
    const int t = threadIdx.x;

    #pragma unroll
    for (int it = 0; it < 16; ++it) {
        f32x4 v = p4[it * 256 + t];
        f32x4 r;
        r.x = fmaf(v.x, scale, shift);
        r.y = fmaf(v.y, scale, shift);
        r.z = fmaf(v.z, scale, shift);
        r.w = fmaf(v.w, scale, shift);
        __builtin_nontemporal_store(r, &o4[it * 256 + t]);
    }
}

// ---------------------------------------------------------------------------
extern "C" void kernel_launch(void* const* d_in, const int* in_sizes, int n_in,
                              void* d_out, int out_size, void* d_ws, size_t ws_size,
                              hipStream_t stream) {
    const float* im           = (const float*)d_in[0];
    const float* running_mean = (const float*)d_in[1];
    const float* running_std  = (const float*)d_in[2];
    const int*   c_trg        = (const int*)d_in[3];
    const int*   c_org        = (const int*)d_in[4];
    float* out = (float*)d_out;

    // Workspace layout (floats):
    //   mean[4096] | std[4096] | rm_final[2560] | rs_final[2560]
    float* ws      = (float*)d_ws;
    float* ws_mean = ws;
    float* ws_std  = ws + B_ * C_;
    float* ws_rm   = ws + 2 * B_ * C_;
    float* ws_rs   = ws + 2 * B_ * C_ + 2 * CDIM * C_;

    const int planes = B_ * C_;   // 4096

    cin_stats<<<planes, 256, 0, stream>>>(im, ws_mean, ws_std);
    cin_scan<<<2 * CDIM, 256, 0, stream>>>(running_mean, running_std, c_org,
                                           ws_mean, ws_std, ws_rm, ws_rs);
    cin_norm<<<planes, 256, 0, stream>>>(im, ws_mean, ws_std, ws_rm, ws_rs,
                                         c_trg, out);
}